// Round 9
// baseline (283.858 us; speedup 1.0000x reference)
//
#include <hip/hip_runtime.h>
#include <math.h>

#define L_SEQ 2048
#define E_DIM 2048
#define H_NUM 16
#define D_HEAD 128

typedef __attribute__((ext_vector_type(8))) _Float16 half8;
typedef __attribute__((ext_vector_type(4))) _Float16 half4;
typedef __attribute__((ext_vector_type(4))) float floatx4;

// async global->LDS, 16B per lane. LDS dest is wave-uniform base + lane*16.
static __device__ __forceinline__ void gload16(const void* g, void* lds) {
  __builtin_amdgcn_global_load_lds(
      (const __attribute__((address_space(1))) void*)g,
      (__attribute__((address_space(3))) void*)lds, 16, 0, 0);
}

// ---------------------------------------------------------------------------
// Fused fp32 -> fp16 conversion of x, in_proj_w, out_proj_w (one launch).
// ---------------------------------------------------------------------------
__global__ __launch_bounds__(256)
void cvt3_f32_f16(const float* __restrict__ a, _Float16* __restrict__ oa, int na,
                  const float* __restrict__ b, _Float16* __restrict__ ob, int nb,
                  const float* __restrict__ c, _Float16* __restrict__ oc, int nc) {
  int i = (blockIdx.x * 256 + threadIdx.x) * 8;
  const float* src;
  _Float16* dst;
  if (i < na) {
    src = a + i; dst = oa + i;
  } else if (i < na + nb) {
    src = b + (i - na); dst = ob + (i - na);
  } else if (i < na + nb + nc) {
    src = c + (i - na - nb); dst = oc + (i - na - nb);
  } else {
    return;
  }
  float4 p = *(const float4*)src;
  float4 q = *(const float4*)(src + 4);
  half8 h = {(_Float16)p.x, (_Float16)p.y, (_Float16)p.z, (_Float16)p.w,
             (_Float16)q.x, (_Float16)q.y, (_Float16)q.z, (_Float16)q.w};
  *(half8*)dst = h;
}

// ---------------------------------------------------------------------------
// QKV GEMM v4 (R8-verified, dropped below attn in top-5): 128x384 tile,
// grid (16,16) = 256 blocks full chip, BK=64, 512 thr = 8 waves (2M x 4N),
// counted-vmcnt granule ring, swizzle c^((row>>1)&3), XCD block swizzle.
// ---------------------------------------------------------------------------
__global__ __launch_bounds__(512, 1)
void gemm_qkv(const _Float16* __restrict__ A, const _Float16* __restrict__ B,
              const float* __restrict__ bias, _Float16* __restrict__ qk,
              _Float16* __restrict__ vt) {
  constexpr int K = E_DIM;  // 2048, 32 K-tiles of 64
  __shared__ __align__(16) char smem[131072];
  char* const Asm = smem;            // 4 slots x 8KB  ([128 r][32 h])
  char* const Bsm = smem + 32768;    // 4 slots x 24KB ([384 r][32 h])

  const int tid = threadIdx.x;
  const int wave = tid >> 6, lane = tid & 63;
  const int l15 = lane & 15, quad = lane >> 4;
  const int wm = wave >> 2, wn = wave & 3;

  const int lid = blockIdx.y * 16 + blockIdx.x;
  const int swz = (lid & 7) * 32 + (lid >> 3);
  const int brow = (swz >> 4) * 128, bcol = (swz & 15) * 384;

  const _Float16* Ag = A + (size_t)brow * K;
  const _Float16* Bg = B + (size_t)bcol * K;

  // stage granule (T,kh): A 512 chunks (1 load/thr) + B 1536 chunks (3/thr).
  auto stg = [&](int T, int kh) {
    char* aslot = Asm + ((T & 1) * 2 + kh) * 8192;
    char* bslot = Bsm + ((T & 1) * 2 + kh) * 24576;
    {
      int row = tid >> 2, c = tid & 3;
      gload16(Ag + (size_t)row * K + T * 64 + kh * 32 +
                  ((c ^ ((row >> 1) & 3)) * 8),
              aslot + (tid & ~63) * 16);
    }
#pragma unroll
    for (int j = 0; j < 3; ++j) {
      int mb = j * 512 + (tid & ~63);
      int m = mb + (tid & 63);
      int row = m >> 2, c = m & 3;
      gload16(Bg + (size_t)row * K + T * 64 + kh * 32 +
                  ((c ^ ((row >> 1) & 3)) * 8),
              bslot + mb * 16);
    }
  };

  floatx4 acc[4][6];
#pragma unroll
  for (int i = 0; i < 4; ++i)
#pragma unroll
    for (int j = 0; j < 6; ++j) acc[i][j] = (floatx4){0.f, 0.f, 0.f, 0.f};

  auto compute_phase = [&](int T, int ks) {
    const char* Ab = Asm + ((T & 1) * 2 + ks) * 8192;
    const char* Bb = Bsm + ((T & 1) * 2 + ks) * 24576;
    half8 af[4], bf[6];
#pragma unroll
    for (int t = 0; t < 4; ++t) {
      int r = wm * 64 + t * 16 + l15;
      af[t] = *(const half8*)(Ab + (size_t)r * 64 +
                              ((quad ^ ((r >> 1) & 3)) * 16));
    }
#pragma unroll
    for (int t = 0; t < 6; ++t) {
      int r = wn * 96 + t * 16 + l15;
      bf[t] = *(const half8*)(Bb + (size_t)r * 64 +
                              ((quad ^ ((r >> 1) & 3)) * 16));
    }
#pragma unroll
    for (int i = 0; i < 4; ++i)
#pragma unroll
      for (int j = 0; j < 6; ++j)
        acc[i][j] = __builtin_amdgcn_mfma_f32_16x16x32_f16(af[i], bf[j],
                                                           acc[i][j], 0, 0, 0);
  };

  // prologue FIFO: (0,0),(0,1),(1,0) = 12 loads
  stg(0, 0); stg(0, 1); stg(1, 0);

  for (int T = 0; T < 31; ++T) {
    // ---- phase A (ks=0): consumes (T,0) ----
    __builtin_amdgcn_sched_barrier(0);
    asm volatile("s_waitcnt vmcnt(8) lgkmcnt(0)" ::: "memory");
    __builtin_amdgcn_s_barrier();
    __builtin_amdgcn_sched_barrier(0);
    stg(T + 1, 1);
    compute_phase(T, 0);
    // ---- phase B (ks=1): consumes (T,1) ----
    __builtin_amdgcn_sched_barrier(0);
    asm volatile("s_waitcnt vmcnt(8) lgkmcnt(0)" ::: "memory");
    __builtin_amdgcn_s_barrier();
    __builtin_amdgcn_sched_barrier(0);
    if (T < 30) stg(T + 2, 0);
    compute_phase(T, 1);
  }
  // ---- T = 31 peeled (drain) ----
  __builtin_amdgcn_sched_barrier(0);
  asm volatile("s_waitcnt vmcnt(4) lgkmcnt(0)" ::: "memory");
  __builtin_amdgcn_s_barrier();
  __builtin_amdgcn_sched_barrier(0);
  compute_phase(31, 0);
  __builtin_amdgcn_sched_barrier(0);
  asm volatile("s_waitcnt vmcnt(0) lgkmcnt(0)" ::: "memory");
  __builtin_amdgcn_s_barrier();
  __builtin_amdgcn_sched_barrier(0);
  compute_phase(31, 1);

  // ---- epilogue: per 16-col fragment qk fp16 or vt transposed fp16 ----
  const int crow = brow + wm * 64;
  const int ccol0 = bcol + wn * 96;
#pragma unroll
  for (int j = 0; j < 6; ++j) {
    int col = ccol0 + j * 16 + l15;
    float bb = bias[col];
    if (col < 2 * E_DIM) {
#pragma unroll
      for (int i = 0; i < 4; ++i)
#pragma unroll
        for (int r = 0; r < 4; ++r)
          qk[(size_t)(crow + i * 16 + quad * 4 + r) * (2 * E_DIM) + col] =
              (_Float16)(acc[i][j][r] + bb);
    } else {
      int vrow = col - 2 * E_DIM;
#pragma unroll
      for (int i = 0; i < 4; ++i) {
        int rbase = crow + i * 16 + quad * 4;
        half4 h = {(_Float16)(acc[i][j][0] + bb), (_Float16)(acc[i][j][1] + bb),
                   (_Float16)(acc[i][j][2] + bb), (_Float16)(acc[i][j][3] + bb)};
        *(half4*)&vt[(size_t)vrow * L_SEQ + rbase] = h;
      }
    }
  }
}

// ---------------------------------------------------------------------------
// Out-proj GEMM v3: same counted-vmcnt ring as gemm_qkv v4, sized 128x128 ->
// grid (16,16) = 256 blocks. 512 thr = 8 waves (2M x 4N), wave tile 64x32.
// LDS 64KB = 4 slots x (A 8KB + B 8KB) -> 2 blocks/CU capacity. stg = 2
// loads/thread -> prologue 6 outstanding, steady vmcnt(4), drain 2 -> 0
// (v4's 12/8/4/0 FIFO scaled to 2-load granules). Replaces the old 2-barrier
// 128x64/4-wave kernel (worst MFMA:overhead ratio in the pipeline).
// ---------------------------------------------------------------------------
__global__ __launch_bounds__(512, 2)
void gemm_out(const _Float16* __restrict__ A, const _Float16* __restrict__ B,
              const float* __restrict__ bias, float* __restrict__ C) {
  constexpr int K = E_DIM;   // 2048, 32 K-tiles of 64
  constexpr int N = E_DIM;
  __shared__ __align__(16) char smem[65536];
  char* const Asm = smem;            // 4 slots x 8KB ([128 r][32 h])
  char* const Bsm = smem + 32768;    // 4 slots x 8KB ([128 r][32 h])

  const int tid = threadIdx.x;
  const int wave = tid >> 6, lane = tid & 63;
  const int l15 = lane & 15, quad = lane >> 4;
  const int wm = wave >> 2, wn = wave & 3;

  const int lid = blockIdx.y * 16 + blockIdx.x;
  const int swz = (lid & 7) * 32 + (lid >> 3);
  const int brow = (swz >> 4) * 128, bcol = (swz & 15) * 128;

  const _Float16* Ag = A + (size_t)brow * K;
  const _Float16* Bg = B + (size_t)bcol * K;

  // stage granule (T,kh): A 512 chunks (1/thr) + B 512 chunks (1/thr).
  auto stg = [&](int T, int kh) {
    char* aslot = Asm + ((T & 1) * 2 + kh) * 8192;
    char* bslot = Bsm + ((T & 1) * 2 + kh) * 8192;
    int row = tid >> 2, c = tid & 3;
    int goff = T * 64 + kh * 32 + ((c ^ ((row >> 1) & 3)) * 8);
    gload16(Ag + (size_t)row * K + goff, aslot + (tid & ~63) * 16);
    gload16(Bg + (size_t)row * K + goff, bslot + (tid & ~63) * 16);
  };

  floatx4 acc[4][2];
#pragma unroll
  for (int i = 0; i < 4; ++i)
#pragma unroll
    for (int j = 0; j < 2; ++j) acc[i][j] = (floatx4){0.f, 0.f, 0.f, 0.f};

  auto compute_phase = [&](int T, int ks) {
    const char* Ab = Asm + ((T & 1) * 2 + ks) * 8192;
    const char* Bb = Bsm + ((T & 1) * 2 + ks) * 8192;
    half8 af[4], bf[2];
#pragma unroll
    for (int t = 0; t < 4; ++t) {
      int r = wm * 64 + t * 16 + l15;
      af[t] = *(const half8*)(Ab + (size_t)r * 64 +
                              ((quad ^ ((r >> 1) & 3)) * 16));
    }
#pragma unroll
    for (int t = 0; t < 2; ++t) {
      int r = wn * 32 + t * 16 + l15;
      bf[t] = *(const half8*)(Bb + (size_t)r * 64 +
                              ((quad ^ ((r >> 1) & 3)) * 16));
    }
#pragma unroll
    for (int i = 0; i < 4; ++i)
#pragma unroll
      for (int j = 0; j < 2; ++j)
        acc[i][j] = __builtin_amdgcn_mfma_f32_16x16x32_f16(af[i], bf[j],
                                                           acc[i][j], 0, 0, 0);
  };

  // prologue FIFO: (0,0),(0,1),(1,0) = 6 loads
  stg(0, 0); stg(0, 1); stg(1, 0);

  for (int T = 0; T < 31; ++T) {
    // ---- phase A (ks=0): consumes (T,0) ----
    __builtin_amdgcn_sched_barrier(0);
    asm volatile("s_waitcnt vmcnt(4) lgkmcnt(0)" ::: "memory");
    __builtin_amdgcn_s_barrier();
    __builtin_amdgcn_sched_barrier(0);
    stg(T + 1, 1);
    compute_phase(T, 0);
    // ---- phase B (ks=1): consumes (T,1) ----
    __builtin_amdgcn_sched_barrier(0);
    asm volatile("s_waitcnt vmcnt(4) lgkmcnt(0)" ::: "memory");
    __builtin_amdgcn_s_barrier();
    __builtin_amdgcn_sched_barrier(0);
    if (T < 30) stg(T + 2, 0);
    compute_phase(T, 1);
  }
  // ---- T = 31 peeled (drain) ----
  __builtin_amdgcn_sched_barrier(0);
  asm volatile("s_waitcnt vmcnt(2) lgkmcnt(0)" ::: "memory");
  __builtin_amdgcn_s_barrier();
  __builtin_amdgcn_sched_barrier(0);
  compute_phase(31, 0);
  __builtin_amdgcn_sched_barrier(0);
  asm volatile("s_waitcnt vmcnt(0) lgkmcnt(0)" ::: "memory");
  __builtin_amdgcn_s_barrier();
  __builtin_amdgcn_sched_barrier(0);
  compute_phase(31, 1);

  // ---- epilogue: fp32 C + bias ----
  const int crow = brow + wm * 64;
  const int ccol0 = bcol + wn * 32;
#pragma unroll
  for (int j = 0; j < 2; ++j) {
    int col = ccol0 + j * 16 + l15;
    float bb = bias[col];
#pragma unroll
    for (int i = 0; i < 4; ++i)
#pragma unroll
      for (int r = 0; r < 4; ++r)
        C[(size_t)(crow + i * 16 + quad * 4 + r) * N + col] =
            acc[i][j][r] + bb;
  }
}

// ---------------------------------------------------------------------------
// MFMA flash attention v5 (proven ~70us local optimum — rounds 1-5 all lost).
// Grid (H, L/128) = 256 blocks, 512 thr = 8 waves. Wave owns 16 q-rows.
// Bc=64 keys/iter, 32 iters, double-buffered K/V LDS, one barrier/iter,
// reg-prefetch of next tile + bias, S^T=K*Q^T trick, no-max softmax.
// ---------------------------------------------------------------------------
__global__ __launch_bounds__(512, 2)
void attn_mfma(const _Float16* __restrict__ qk, const _Float16* __restrict__ vt,
               const float* __restrict__ bias, _Float16* __restrict__ ctx) {
  const int h = blockIdx.x;
  const int q0 = blockIdx.y * 128;
  const int tid = threadIdx.x;
  const int wave = tid >> 6;
  const int lane = tid & 63;
  const int l15 = lane & 15;
  const int quad = lane >> 4;

  __shared__ _Float16 Ks[2][64][136];   // [buf][key][d]
  __shared__ _Float16 Vst[2][128][72];  // [buf][d][key]
  __shared__ _Float16 Ps[128][72];      // [q][key] (same-wave use only)

  // Q fragments (B-operand: B[k=quad*8+j][n=l15=q]):
  half8 qa[4];
  {
    const _Float16* qp = qk + (size_t)(q0 + wave * 16 + l15) * (2 * E_DIM) +
                         h * D_HEAD + quad * 8;
#pragma unroll
    for (int ks = 0; ks < 4; ++ks) qa[ks] = *(const half8*)(qp + ks * 32);
  }

  float l_i = 0.f;
  floatx4 o[8];
#pragma unroll
  for (int t = 0; t < 8; ++t) o[t] = (floatx4){0.f, 0.f, 0.f, 0.f};

  const float scale = 0.088388347648318447f;  // 1/sqrt(128)

  // staging (512 threads, 2 chunks each of K and V):
  half8 kreg[2], vreg[2];
  floatx4 bcur[4], bnxt[4];
#pragma unroll
  for (int c = 0; c < 2; ++c) {
    int m = c * 512 + tid;
    kreg[c] = *(const half8*)(qk + (size_t)(m >> 4) * (2 * E_DIM) + E_DIM +
                              h * D_HEAD + (m & 15) * 8);
    vreg[c] = *(const half8*)(vt + (size_t)(h * D_HEAD + (m >> 3)) * L_SEQ +
                              (m & 7) * 8);
  }
#pragma unroll
  for (int t = 0; t < 4; ++t)
    bcur[t] = *(const floatx4*)&bias[(size_t)(q0 + wave * 16 + l15) * L_SEQ +
                                    16 * t + quad * 4];
#pragma unroll
  for (int c = 0; c < 2; ++c) {
    int m = c * 512 + tid;
    *(half8*)&Ks[0][m >> 4][(m & 15) * 8] = kreg[c];
    *(half8*)&Vst[0][m >> 3][(m & 7) * 8] = vreg[c];
  }

#pragma unroll 2
  for (int it = 0; it < 32; ++it) {
    const int cur = it & 1, nxt = cur ^ 1;
    const int kt = it * 64;
    __syncthreads();  // buf[cur] writes visible; buf[nxt] readers (it-1) done

    if (it < 31) {
#pragma unroll
      for (int c = 0; c < 2; ++c) {
        int m = c * 512 + tid;
        kreg[c] = *(const half8*)(qk + (size_t)(kt + 64 + (m >> 4)) * (2 * E_DIM) +
                                  E_DIM + h * D_HEAD + (m & 15) * 8);
        vreg[c] = *(const half8*)(vt + (size_t)(h * D_HEAD + (m >> 3)) * L_SEQ +
                                  kt + 64 + (m & 7) * 8);
      }
#pragma unroll
      for (int t = 0; t < 4; ++t)
        bnxt[t] = *(const floatx4*)&bias[(size_t)(q0 + wave * 16 + l15) * L_SEQ +
                                         kt + 64 + 16 * t + quad * 4];
    }

    // ---- S^T = K Q^T : col=l15=q, row=quad*4+reg=key(within 16t) ----
    floatx4 st[4];
#pragma unroll
    for (int t = 0; t < 4; ++t) st[t] = (floatx4){0.f, 0.f, 0.f, 0.f};
#pragma unroll
    for (int ks = 0; ks < 4; ++ks)
#pragma unroll
      for (int t = 0; t < 4; ++t) {
        half8 kf = *(const half8*)&Ks[cur][16 * t + l15][ks * 32 + quad * 8];
        st[t] = __builtin_amdgcn_mfma_f32_16x16x32_f16(kf, qa[ks], st[t], 0, 0, 0);
      }

    // ---- softmax (no max subtraction) + P^T pack -> Ps[q][key] ----
    {
      float ls = 0.f;
      float ps[4][4];
#pragma unroll
      for (int t = 0; t < 4; ++t)
#pragma unroll
        for (int r = 0; r < 4; ++r) {
          float p = __expf(fmaf(st[t][r], scale, bcur[t][r]));
          ps[t][r] = p;
          ls += p;
        }
      ls += __shfl_xor(ls, 16);
      ls += __shfl_xor(ls, 32);
      l_i += ls;
#pragma unroll
      for (int t = 0; t < 4; ++t) {
        half4 hp = {(_Float16)ps[t][0], (_Float16)ps[t][1],
                    (_Float16)ps[t][2], (_Float16)ps[t][3]};
        *(half4*)&Ps[wave * 16 + l15][16 * t + quad * 4] = hp;
      }
    }

    // ---- O += P V (A=P own rows; B=V^T; same-wave, no barrier) ----
    half8 pa[2];
#pragma unroll
    for (int ks = 0; ks < 2; ++ks)
      pa[ks] = *(const half8*)&Ps[wave * 16 + l15][ks * 32 + quad * 8];
#pragma unroll
    for (int t = 0; t < 8; ++t)
#pragma unroll
      for (int ks = 0; ks < 2; ++ks) {
        half8 vf = *(const half8*)&Vst[cur][16 * t + l15][ks * 32 + quad * 8];
        o[t] = __builtin_amdgcn_mfma_f32_16x16x32_f16(pa[ks], vf, o[t], 0, 0, 0);
      }

    if (it < 31) {
#pragma unroll
      for (int c = 0; c < 2; ++c) {
        int m = c * 512 + tid;
        *(half8*)&Ks[nxt][m >> 4][(m & 15) * 8] = kreg[c];
        *(half8*)&Vst[nxt][m >> 3][(m & 7) * 8] = vreg[c];
      }
#pragma unroll
      for (int t = 0; t < 4; ++t) bcur[t] = bnxt[t];
    }
  }

  // ---- epilogue: ctx = O / l. l lives at lane l15=q; o rows are quad*4+r ----
  float inv[4];
#pragma unroll
  for (int r = 0; r < 4; ++r) inv[r] = 1.f / __shfl(l_i, quad * 4 + r);
#pragma unroll
  for (int t = 0; t < 8; ++t)
#pragma unroll
    for (int r = 0; r < 4; ++r) {
      int row = q0 + wave * 16 + quad * 4 + r;
      ctx[(size_t)row * E_DIM + h * D_HEAD + 16 * t + l15] =
          (_Float16)(o[t][r] * inv[r]);
    }
}

// ---------------------------------------------------------------------------
extern "C" void kernel_launch(void* const* d_in, const int* in_sizes, int n_in,
                              void* d_out, int out_size, void* d_ws, size_t ws_size,
                              hipStream_t stream) {
  const float* x          = (const float*)d_in[0];
  const float* bias_mat   = (const float*)d_in[1];
  const float* in_proj_w  = (const float*)d_in[2];
  const float* in_proj_b  = (const float*)d_in[3];
  const float* out_proj_w = (const float*)d_in[4];
  const float* out_proj_b = (const float*)d_in[5];
  float* out = (float*)d_out;

  _Float16* x16 = (_Float16*)d_ws;                         // L*E
  _Float16* w1  = x16 + (size_t)L_SEQ * E_DIM;             // 3E*E
  _Float16* w2  = w1 + (size_t)3 * E_DIM * E_DIM;          // E*E
  _Float16* qk  = w2 + (size_t)E_DIM * E_DIM;              // L*2E
  _Float16* vt  = qk + (size_t)L_SEQ * 2 * E_DIM;          // E*L
  _Float16* ctx = vt + (size_t)E_DIM * L_SEQ;              // L*E

  dim3 blk(256);
  const int nx = L_SEQ * E_DIM, nw1 = 3 * E_DIM * E_DIM, nw2 = E_DIM * E_DIM;

  cvt3_f32_f16<<<(nx + nw1 + nw2) / 2048, blk, 0, stream>>>(
      x, x16, nx, in_proj_w, w1, nw1, out_proj_w, w2, nw2);

  gemm_qkv<<<dim3(16, 16), dim3(512), 0, stream>>>(x16, w1, in_proj_b, qk, vt);

  attn_mfma<<<dim3(H_NUM, L_SEQ / 128), dim3(512), 0, stream>>>(qk, vt, bias_mat,
                                                                ctx);

  gemm_out<<<dim3(16, 16), dim3(512), 0, stream>>>(ctx, w2, out_proj_b, out);
}

// Round 10
// 277.682 us; speedup vs baseline: 1.0222x; 1.0222x over previous
//
#include <hip/hip_runtime.h>
#include <math.h>

#define L_SEQ 2048
#define E_DIM 2048
#define H_NUM 16
#define D_HEAD 128

typedef __attribute__((ext_vector_type(8))) _Float16 half8;
typedef __attribute__((ext_vector_type(4))) _Float16 half4;
typedef __attribute__((ext_vector_type(4))) float floatx4;

// async global->LDS, 16B per lane. LDS dest is wave-uniform base + lane*16.
static __device__ __forceinline__ void gload16(const void* g, void* lds) {
  __builtin_amdgcn_global_load_lds(
      (const __attribute__((address_space(1))) void*)g,
      (__attribute__((address_space(3))) void*)lds, 16, 0, 0);
}

// ---------------------------------------------------------------------------
// Fused fp32 -> fp16 conversion of x, in_proj_w, out_proj_w (one launch).
// ---------------------------------------------------------------------------
__global__ __launch_bounds__(256)
void cvt3_f32_f16(const float* __restrict__ a, _Float16* __restrict__ oa, int na,
                  const float* __restrict__ b, _Float16* __restrict__ ob, int nb,
                  const float* __restrict__ c, _Float16* __restrict__ oc, int nc) {
  int i = (blockIdx.x * 256 + threadIdx.x) * 8;
  const float* src;
  _Float16* dst;
  if (i < na) {
    src = a + i; dst = oa + i;
  } else if (i < na + nb) {
    src = b + (i - na); dst = ob + (i - na);
  } else if (i < na + nb + nc) {
    src = c + (i - na - nb); dst = oc + (i - na - nb);
  } else {
    return;
  }
  float4 p = *(const float4*)src;
  float4 q = *(const float4*)(src + 4);
  half8 h = {(_Float16)p.x, (_Float16)p.y, (_Float16)p.z, (_Float16)p.w,
             (_Float16)q.x, (_Float16)q.y, (_Float16)q.z, (_Float16)q.w};
  *(half8*)dst = h;
}

// ---------------------------------------------------------------------------
// QKV GEMM v4 (R8-verified): 128x384 tile, grid (16,16) = 256 blocks full
// chip, BK=64, 512 thr = 8 waves (2M x 4N), counted-vmcnt granule ring,
// swizzle c^((row>>1)&3), XCD block swizzle.
// ---------------------------------------------------------------------------
__global__ __launch_bounds__(512, 1)
void gemm_qkv(const _Float16* __restrict__ A, const _Float16* __restrict__ B,
              const float* __restrict__ bias, _Float16* __restrict__ qk,
              _Float16* __restrict__ vt) {
  constexpr int K = E_DIM;  // 2048, 32 K-tiles of 64
  __shared__ __align__(16) char smem[131072];
  char* const Asm = smem;            // 4 slots x 8KB  ([128 r][32 h])
  char* const Bsm = smem + 32768;    // 4 slots x 24KB ([384 r][32 h])

  const int tid = threadIdx.x;
  const int wave = tid >> 6, lane = tid & 63;
  const int l15 = lane & 15, quad = lane >> 4;
  const int wm = wave >> 2, wn = wave & 3;

  const int lid = blockIdx.y * 16 + blockIdx.x;
  const int swz = (lid & 7) * 32 + (lid >> 3);
  const int brow = (swz >> 4) * 128, bcol = (swz & 15) * 384;

  const _Float16* Ag = A + (size_t)brow * K;
  const _Float16* Bg = B + (size_t)bcol * K;

  // stage granule (T,kh): A 512 chunks (1 load/thr) + B 1536 chunks (3/thr).
  auto stg = [&](int T, int kh) {
    char* aslot = Asm + ((T & 1) * 2 + kh) * 8192;
    char* bslot = Bsm + ((T & 1) * 2 + kh) * 24576;
    {
      int row = tid >> 2, c = tid & 3;
      gload16(Ag + (size_t)row * K + T * 64 + kh * 32 +
                  ((c ^ ((row >> 1) & 3)) * 8),
              aslot + (tid & ~63) * 16);
    }
#pragma unroll
    for (int j = 0; j < 3; ++j) {
      int mb = j * 512 + (tid & ~63);
      int m = mb + (tid & 63);
      int row = m >> 2, c = m & 3;
      gload16(Bg + (size_t)row * K + T * 64 + kh * 32 +
                  ((c ^ ((row >> 1) & 3)) * 8),
              bslot + mb * 16);
    }
  };

  floatx4 acc[4][6];
#pragma unroll
  for (int i = 0; i < 4; ++i)
#pragma unroll
    for (int j = 0; j < 6; ++j) acc[i][j] = (floatx4){0.f, 0.f, 0.f, 0.f};

  auto compute_phase = [&](int T, int ks) {
    const char* Ab = Asm + ((T & 1) * 2 + ks) * 8192;
    const char* Bb = Bsm + ((T & 1) * 2 + ks) * 24576;
    half8 af[4], bf[6];
#pragma unroll
    for (int t = 0; t < 4; ++t) {
      int r = wm * 64 + t * 16 + l15;
      af[t] = *(const half8*)(Ab + (size_t)r * 64 +
                              ((quad ^ ((r >> 1) & 3)) * 16));
    }
#pragma unroll
    for (int t = 0; t < 6; ++t) {
      int r = wn * 96 + t * 16 + l15;
      bf[t] = *(const half8*)(Bb + (size_t)r * 64 +
                              ((quad ^ ((r >> 1) & 3)) * 16));
    }
#pragma unroll
    for (int i = 0; i < 4; ++i)
#pragma unroll
      for (int j = 0; j < 6; ++j)
        acc[i][j] = __builtin_amdgcn_mfma_f32_16x16x32_f16(af[i], bf[j],
                                                           acc[i][j], 0, 0, 0);
  };

  // prologue FIFO: (0,0),(0,1),(1,0) = 12 loads
  stg(0, 0); stg(0, 1); stg(1, 0);

  for (int T = 0; T < 31; ++T) {
    // ---- phase A (ks=0): consumes (T,0) ----
    __builtin_amdgcn_sched_barrier(0);
    asm volatile("s_waitcnt vmcnt(8) lgkmcnt(0)" ::: "memory");
    __builtin_amdgcn_s_barrier();
    __builtin_amdgcn_sched_barrier(0);
    stg(T + 1, 1);
    compute_phase(T, 0);
    // ---- phase B (ks=1): consumes (T,1) ----
    __builtin_amdgcn_sched_barrier(0);
    asm volatile("s_waitcnt vmcnt(8) lgkmcnt(0)" ::: "memory");
    __builtin_amdgcn_s_barrier();
    __builtin_amdgcn_sched_barrier(0);
    if (T < 30) stg(T + 2, 0);
    compute_phase(T, 1);
  }
  // ---- T = 31 peeled (drain) ----
  __builtin_amdgcn_sched_barrier(0);
  asm volatile("s_waitcnt vmcnt(4) lgkmcnt(0)" ::: "memory");
  __builtin_amdgcn_s_barrier();
  __builtin_amdgcn_sched_barrier(0);
  compute_phase(31, 0);
  __builtin_amdgcn_sched_barrier(0);
  asm volatile("s_waitcnt vmcnt(0) lgkmcnt(0)" ::: "memory");
  __builtin_amdgcn_s_barrier();
  __builtin_amdgcn_sched_barrier(0);
  compute_phase(31, 1);

  // ---- epilogue: per 16-col fragment qk fp16 or vt transposed fp16 ----
  const int crow = brow + wm * 64;
  const int ccol0 = bcol + wn * 96;
#pragma unroll
  for (int j = 0; j < 6; ++j) {
    int col = ccol0 + j * 16 + l15;
    float bb = bias[col];
    if (col < 2 * E_DIM) {
#pragma unroll
      for (int i = 0; i < 4; ++i)
#pragma unroll
        for (int r = 0; r < 4; ++r)
          qk[(size_t)(crow + i * 16 + quad * 4 + r) * (2 * E_DIM) + col] =
              (_Float16)(acc[i][j][r] + bb);
    } else {
      int vrow = col - 2 * E_DIM;
#pragma unroll
      for (int i = 0; i < 4; ++i) {
        int rbase = crow + i * 16 + quad * 4;
        half4 h = {(_Float16)(acc[i][j][0] + bb), (_Float16)(acc[i][j][1] + bb),
                   (_Float16)(acc[i][j][2] + bb), (_Float16)(acc[i][j][3] + bb)};
        *(half4*)&vt[(size_t)vrow * L_SEQ + rbase] = h;
      }
    }
  }
}

// ---------------------------------------------------------------------------
// MFMA GEMM (NT) v2: out-proj (R8-best config: 512 blocks x 256 thr,
// 2 blocks/CU — inter-block barrier overlap; the R9 ring port at 256 blocks
// = 1 block/CU was neutral-to-worse, reverted per A/B).
// ---------------------------------------------------------------------------
template <int TM, int TN, int WR, int WC>
__global__ __launch_bounds__(256)
void gemm_mfma(const _Float16* __restrict__ A, const _Float16* __restrict__ B,
               const float* __restrict__ bias, float* __restrict__ C,
               int M, int N, int K) {
  constexpr int RT = TM / (16 * WR);
  constexpr int CT = TN / (16 * WC);
  constexpr int ACH = TM / 8;
  constexpr int NCH = (TM + TN) / 32;

  __shared__ _Float16 As[2][TM * 64];
  __shared__ _Float16 Bs[2][TN * 64];

  const int tid = threadIdx.x;
  const int wave = tid >> 6, lane = tid & 63;
  const int l15 = lane & 15, quad = lane >> 4;
  const int wr = wave / WC, wc = wave % WC;
  const int row0 = blockIdx.y * TM, col0 = blockIdx.x * TN;

  const int srow = lane >> 3;
  const int gc = (lane & 7) ^ srow;

  auto stage = [&](int buf, int k0) {
#pragma unroll
    for (int c = 0; c < NCH; ++c) {
      int chunk = wave * NCH + c;
      if (chunk < ACH) {
        int row = chunk * 8 + srow;
        gload16((const char*)(A + (size_t)(row0 + row) * K + k0) + gc * 16,
                (char*)&As[buf][0] + chunk * 1024);
      } else {
        int bch = chunk - ACH;
        int row = bch * 8 + srow;
        gload16((const char*)(B + (size_t)(col0 + row) * K + k0) + gc * 16,
                (char*)&Bs[buf][0] + bch * 1024);
      }
    }
  };

  floatx4 acc[RT][CT];
#pragma unroll
  for (int i = 0; i < RT; ++i)
#pragma unroll
    for (int j = 0; j < CT; ++j) acc[i][j] = (floatx4){0.f, 0.f, 0.f, 0.f};

  const int niter = K / 64;
  stage(0, 0);

  for (int it = 0; it < niter; ++it) {
    const int cur = it & 1;
    __syncthreads();
    if (it + 1 < niter) stage(cur ^ 1, (it + 1) * 64);

#pragma unroll
    for (int ks = 0; ks < 2; ++ks) {
      half8 af[RT], bf[CT];
#pragma unroll
      for (int t = 0; t < RT; ++t) {
        int r = wr * (16 * RT) + t * 16 + l15;
        af[t] = *(const half8*)&As[cur][r * 64 + (((ks * 4 + quad) ^ (r & 7)) * 8)];
      }
#pragma unroll
      for (int t = 0; t < CT; ++t) {
        int r = wc * (16 * CT) + t * 16 + l15;
        bf[t] = *(const half8*)&Bs[cur][r * 64 + (((ks * 4 + quad) ^ (r & 7)) * 8)];
      }
#pragma unroll
      for (int tr = 0; tr < RT; ++tr)
#pragma unroll
        for (int tc = 0; tc < CT; ++tc)
          acc[tr][tc] = __builtin_amdgcn_mfma_f32_16x16x32_f16(
              af[tr], bf[tc], acc[tr][tc], 0, 0, 0);
    }
  }

  const int crow = row0 + wr * (16 * RT);
  const int ccol = col0 + wc * (16 * CT);

#pragma unroll
  for (int tc = 0; tc < CT; ++tc) {
    int col = ccol + tc * 16 + l15;
    float bb = bias[col];
#pragma unroll
    for (int tr = 0; tr < RT; ++tr)
#pragma unroll
      for (int r = 0; r < 4; ++r)
        C[(size_t)(crow + tr * 16 + quad * 4 + r) * N + col] =
            acc[tr][tc][r] + bb;
  }
}

// ---------------------------------------------------------------------------
// MFMA flash attention v5 (proven ~70us local optimum — 6 variants all lost;
// LDS-pipe-bound: ~34 b128 reads/iter/wave + 9.96M conflict cycles ~= 60 of
// its ~71us; block geometry forced by grid>=256 constraint).
// Grid (H, L/128) = 256 blocks, 512 thr = 8 waves. Wave owns 16 q-rows.
// Bc=64 keys/iter, 32 iters, double-buffered K/V LDS, one barrier/iter,
// reg-prefetch of next tile + bias, S^T=K*Q^T trick, no-max softmax.
// ---------------------------------------------------------------------------
__global__ __launch_bounds__(512, 2)
void attn_mfma(const _Float16* __restrict__ qk, const _Float16* __restrict__ vt,
               const float* __restrict__ bias, _Float16* __restrict__ ctx) {
  const int h = blockIdx.x;
  const int q0 = blockIdx.y * 128;
  const int tid = threadIdx.x;
  const int wave = tid >> 6;
  const int lane = tid & 63;
  const int l15 = lane & 15;
  const int quad = lane >> 4;

  __shared__ _Float16 Ks[2][64][136];   // [buf][key][d]
  __shared__ _Float16 Vst[2][128][72];  // [buf][d][key]
  __shared__ _Float16 Ps[128][72];      // [q][key] (same-wave use only)

  // Q fragments (B-operand: B[k=quad*8+j][n=l15=q]):
  half8 qa[4];
  {
    const _Float16* qp = qk + (size_t)(q0 + wave * 16 + l15) * (2 * E_DIM) +
                         h * D_HEAD + quad * 8;
#pragma unroll
    for (int ks = 0; ks < 4; ++ks) qa[ks] = *(const half8*)(qp + ks * 32);
  }

  float l_i = 0.f;
  floatx4 o[8];
#pragma unroll
  for (int t = 0; t < 8; ++t) o[t] = (floatx4){0.f, 0.f, 0.f, 0.f};

  const float scale = 0.088388347648318447f;  // 1/sqrt(128)

  // staging (512 threads, 2 chunks each of K and V):
  half8 kreg[2], vreg[2];
  floatx4 bcur[4], bnxt[4];
#pragma unroll
  for (int c = 0; c < 2; ++c) {
    int m = c * 512 + tid;
    kreg[c] = *(const half8*)(qk + (size_t)(m >> 4) * (2 * E_DIM) + E_DIM +
                              h * D_HEAD + (m & 15) * 8);
    vreg[c] = *(const half8*)(vt + (size_t)(h * D_HEAD + (m >> 3)) * L_SEQ +
                              (m & 7) * 8);
  }
#pragma unroll
  for (int t = 0; t < 4; ++t)
    bcur[t] = *(const floatx4*)&bias[(size_t)(q0 + wave * 16 + l15) * L_SEQ +
                                    16 * t + quad * 4];
#pragma unroll
  for (int c = 0; c < 2; ++c) {
    int m = c * 512 + tid;
    *(half8*)&Ks[0][m >> 4][(m & 15) * 8] = kreg[c];
    *(half8*)&Vst[0][m >> 3][(m & 7) * 8] = vreg[c];
  }

#pragma unroll 2
  for (int it = 0; it < 32; ++it) {
    const int cur = it & 1, nxt = cur ^ 1;
    const int kt = it * 64;
    __syncthreads();  // buf[cur] writes visible; buf[nxt] readers (it-1) done

    if (it < 31) {
#pragma unroll
      for (int c = 0; c < 2; ++c) {
        int m = c * 512 + tid;
        kreg[c] = *(const half8*)(qk + (size_t)(kt + 64 + (m >> 4)) * (2 * E_DIM) +
                                  E_DIM + h * D_HEAD + (m & 15) * 8);
        vreg[c] = *(const half8*)(vt + (size_t)(h * D_HEAD + (m >> 3)) * L_SEQ +
                                  kt + 64 + (m & 7) * 8);
      }
#pragma unroll
      for (int t = 0; t < 4; ++t)
        bnxt[t] = *(const floatx4*)&bias[(size_t)(q0 + wave * 16 + l15) * L_SEQ +
                                         kt + 64 + 16 * t + quad * 4];
    }

    // ---- S^T = K Q^T : col=l15=q, row=quad*4+reg=key(within 16t) ----
    floatx4 st[4];
#pragma unroll
    for (int t = 0; t < 4; ++t) st[t] = (floatx4){0.f, 0.f, 0.f, 0.f};
#pragma unroll
    for (int ks = 0; ks < 4; ++ks)
#pragma unroll
      for (int t = 0; t < 4; ++t) {
        half8 kf = *(const half8*)&Ks[cur][16 * t + l15][ks * 32 + quad * 8];
        st[t] = __builtin_amdgcn_mfma_f32_16x16x32_f16(kf, qa[ks], st[t], 0, 0, 0);
      }

    // ---- softmax (no max subtraction) + P^T pack -> Ps[q][key] ----
    {
      float ls = 0.f;
      float ps[4][4];
#pragma unroll
      for (int t = 0; t < 4; ++t)
#pragma unroll
        for (int r = 0; r < 4; ++r) {
          float p = __expf(fmaf(st[t][r], scale, bcur[t][r]));
          ps[t][r] = p;
          ls += p;
        }
      ls += __shfl_xor(ls, 16);
      ls += __shfl_xor(ls, 32);
      l_i += ls;
#pragma unroll
      for (int t = 0; t < 4; ++t) {
        half4 hp = {(_Float16)ps[t][0], (_Float16)ps[t][1],
                    (_Float16)ps[t][2], (_Float16)ps[t][3]};
        *(half4*)&Ps[wave * 16 + l15][16 * t + quad * 4] = hp;
      }
    }

    // ---- O += P V (A=P own rows; B=V^T; same-wave, no barrier) ----
    half8 pa[2];
#pragma unroll
    for (int ks = 0; ks < 2; ++ks)
      pa[ks] = *(const half8*)&Ps[wave * 16 + l15][ks * 32 + quad * 8];
#pragma unroll
    for (int t = 0; t < 8; ++t)
#pragma unroll
      for (int ks = 0; ks < 2; ++ks) {
        half8 vf = *(const half8*)&Vst[cur][16 * t + l15][ks * 32 + quad * 8];
        o[t] = __builtin_amdgcn_mfma_f32_16x16x32_f16(pa[ks], vf, o[t], 0, 0, 0);
      }

    if (it < 31) {
#pragma unroll
      for (int c = 0; c < 2; ++c) {
        int m = c * 512 + tid;
        *(half8*)&Ks[nxt][m >> 4][(m & 15) * 8] = kreg[c];
        *(half8*)&Vst[nxt][m >> 3][(m & 7) * 8] = vreg[c];
      }
#pragma unroll
      for (int t = 0; t < 4; ++t) bcur[t] = bnxt[t];
    }
  }

  // ---- epilogue: ctx = O / l. l lives at lane l15=q; o rows are quad*4+r ----
  float inv[4];
#pragma unroll
  for (int r = 0; r < 4; ++r) inv[r] = 1.f / __shfl(l_i, quad * 4 + r);
#pragma unroll
  for (int t = 0; t < 8; ++t)
#pragma unroll
    for (int r = 0; r < 4; ++r) {
      int row = q0 + wave * 16 + quad * 4 + r;
      ctx[(size_t)row * E_DIM + h * D_HEAD + 16 * t + l15] =
          (_Float16)(o[t][r] * inv[r]);
    }
}

// ---------------------------------------------------------------------------
extern "C" void kernel_launch(void* const* d_in, const int* in_sizes, int n_in,
                              void* d_out, int out_size, void* d_ws, size_t ws_size,
                              hipStream_t stream) {
  const float* x          = (const float*)d_in[0];
  const float* bias_mat   = (const float*)d_in[1];
  const float* in_proj_w  = (const float*)d_in[2];
  const float* in_proj_b  = (const float*)d_in[3];
  const float* out_proj_w = (const float*)d_in[4];
  const float* out_proj_b = (const float*)d_in[5];
  float* out = (float*)d_out;

  _Float16* x16 = (_Float16*)d_ws;                         // L*E
  _Float16* w1  = x16 + (size_t)L_SEQ * E_DIM;             // 3E*E
  _Float16* w2  = w1 + (size_t)3 * E_DIM * E_DIM;          // E*E
  _Float16* qk  = w2 + (size_t)E_DIM * E_DIM;              // L*2E
  _Float16* vt  = qk + (size_t)L_SEQ * 2 * E_DIM;          // E*L
  _Float16* ctx = vt + (size_t)E_DIM * L_SEQ;              // L*E

  dim3 blk(256);
  const int nx = L_SEQ * E_DIM, nw1 = 3 * E_DIM * E_DIM, nw2 = E_DIM * E_DIM;

  cvt3_f32_f16<<<(nx + nw1 + nw2) / 2048, blk, 0, stream>>>(
      x, x16, nx, in_proj_w, w1, nw1, out_proj_w, w2, nw2);

  gemm_qkv<<<dim3(16, 16), dim3(512), 0, stream>>>(x16, w1, in_proj_b, qk, vt);

  attn_mfma<<<dim3(H_NUM, L_SEQ / 128), dim3(512), 0, stream>>>(qk, vt, bias_mat,
                                                                ctx);

  gemm_mfma<128, 64, 4, 1><<<dim3(E_DIM / 64, L_SEQ / 128), blk, 0, stream>>>(
      ctx, w2, out_proj_b, out, L_SEQ, E_DIM, E_DIM);
}